// Round 16
// baseline (72.923 us; speedup 1.0000x reference)
//
#include <hip/hip_runtime.h>
#include <hip/hip_bf16.h>

#define DEVI static __device__ __forceinline__

typedef __attribute__((ext_vector_type(8))) short short8;
typedef __attribute__((ext_vector_type(16))) float f32x16;
typedef __attribute__((ext_vector_type(2))) unsigned int uintx2;

#define S_LEN 2048
#define D_DIM 128
#define NBATCH 16
#define NT192 11  // ceil(2048/192) tiles per batch
#define TILEB 49152  // 192*256 (K) == 128*384 (V) bytes per tile
// (1/sqrt(128)) * log2(e): base-2 softmax, scale folded into Q conversion
#define QSC ((float)(0.08838834764831845 * 1.4426950408889634))
// fixed softmax shift: P = 2^(score - 8); exact by shift-invariance
#define MFIX 8.0f
#define E8 0.00390625f  // 2^-8, weight of a masked (score 0) position

#if __has_builtin(__builtin_amdgcn_exp2f)
#define EXP2(x) __builtin_amdgcn_exp2f(x)
#else
#define EXP2(x) exp2f(x)
#endif

DEVI unsigned short f2bf(float x) {
  union { float f; unsigned int u; } a; a.f = x;
  unsigned int u = a.u;
  unsigned int r = (u + 0x7fffu + ((u >> 16) & 1u)) >> 16;
  return (unsigned short)r;
}

DEVI unsigned int cvtpk(float lo, float hi) {
  unsigned int r;
  asm volatile("v_cvt_pk_bf16_f32 %0, %1, %2" : "=v"(r) : "v"(lo), "v"(hi));
  return r;
}

// v_permlane32_swap_b32: post: a = {a.lo | b.lo}, b = {a.hi | b.hi}  (R4-verified)
DEVI void plswap(unsigned int& a, unsigned int& b) {
  uintx2 r = __builtin_amdgcn_permlane32_swap(a, b, false, false);
  a = r[0];
  b = r[1];
}

DEVI float xhalf_sum(float x) {
  union { float f; unsigned int u; } a, b;
  a.f = x; b.f = x;
  plswap(a.u, b.u);
  return a.f + b.f;
}

// ---------------- prepass ----------------

// blocks [0,1024): V [b][s][d] fp32 -> Vt 192-key tiles: [b][t:11][d:128][192 keys]
//                  bf16 (384B rows) + per-64-row tile sums
// blocks [1024,3072): K fp32 -> bf16 (row-major unchanged)
__global__ void prep(const float* __restrict__ K, const float* __restrict__ V,
                     unsigned short* __restrict__ Kb, unsigned short* __restrict__ Vt,
                     float* __restrict__ Tsum) {
  __shared__ unsigned short t[64][68];
  const int tt = threadIdx.x;
  if (blockIdx.x >= 1024) {
    const int M4 = (NBATCH * S_LEN * D_DIM) / 4;
    for (int i = (blockIdx.x - 1024) * 256 + tt; i < M4; i += 2048 * 256) {
      const size_t idx = (size_t)i * 4;
      const float4 v = *reinterpret_cast<const float4*>(K + idx);
      ushort4 o;
      o.x = f2bf(v.x); o.y = f2bf(v.y); o.z = f2bf(v.z); o.w = f2bf(v.w);
      *reinterpret_cast<ushort4*>(Kb + idx) = o;
    }
    return;
  }
  const int bid = blockIdx.x;
  const int b = bid >> 6, rem = bid & 63;
  const int st = rem & 31, s0 = st * 64, d0 = (rem >> 5) * 64;
  const int r = tt >> 2, c = (tt & 3) * 16;
  const float* src = V + ((size_t)(b * S_LEN + s0 + r)) * D_DIM + d0 + c;
#pragma unroll
  for (int i = 0; i < 4; i++) {
    float4 v = reinterpret_cast<const float4*>(src)[i];
    t[r][c + 4 * i + 0] = f2bf(v.x);
    t[r][c + 4 * i + 1] = f2bf(v.y);
    t[r][c + 4 * i + 2] = f2bf(v.z);
    t[r][c + 4 * i + 3] = f2bf(v.w);
  }
  __syncthreads();
  // 192-key tile: Vt[((b*11 + st/3)*128 + d)*192 + (st%3)*64 + key]
  unsigned short* dst = Vt + (((size_t)(b * NT192 + st / 3)) * 128 + d0 + r) * 192 +
                        (st % 3) * 64 + c;
#pragma unroll
  for (int i = 0; i < 4; i++) {
    ushort4 o;
    o.x = t[c + 4 * i + 0][r];
    o.y = t[c + 4 * i + 1][r];
    o.z = t[c + 4 * i + 2][r];
    o.w = t[c + 4 * i + 3][r];
    reinterpret_cast<ushort4*>(dst)[i] = o;
  }
  if (tt < 64) {
    float s = 0.0f;
#pragma unroll 8
    for (int rr = 0; rr < 64; rr++) {
      union { float f; unsigned int u; } cv;
      cv.u = ((unsigned int)t[rr][tt]) << 16;
      s += cv.f;
    }
    Tsum[((size_t)b * 32 + st) * 128 + d0 + tt] = s;
  }
}

// SufV[b][t][d] = sum_{t' >= t} Tsum[b][t'][d]; SufV[b][32][d] = 0  (64-granular)
__global__ void sufB(const float* __restrict__ Tsum, float* __restrict__ SufV) {
  const int b = blockIdx.x;
  const int d = threadIdx.x;
  float v[32];
#pragma unroll
  for (int t = 0; t < 32; t++) v[t] = Tsum[((size_t)b * 32 + t) * 128 + d];
  float run = 0.0f;
  SufV[((size_t)b * 33 + 32) * 128 + d] = 0.0f;
#pragma unroll
  for (int t = 31; t >= 0; t--) {
    run += v[t];
    SufV[((size_t)b * 33 + t) * 128 + d] = run;
  }
}

// ---------------- attention kernel ----------------

#define AS1 __attribute__((address_space(1)))
#define AS3 __attribute__((address_space(3)))

// LDS: K double buffer 2x48KB @0, V single 48KB @98304, l region @147456 (1KB)
#define SMEM_BYTES 148480
#define VBASE 98304
#define LBASE 147456

DEVI void run_strip(int j, int b, char* smem, const float* __restrict__ Q,
                    const float* __restrict__ SufV, float* __restrict__ out,
                    const char* KbB, const char* VtB, const int* koff,
                    const int* voff, const int* va, int w, int lane, int ln31,
                    int h, int qs, int kq) {
  const int q0 = j * 64;
  const int kv_end = q0 + 64;
  const int qrow = q0 + 32 * qs + ln31;
  const int T = (64 * (j + 1) + 191) / 192;
  const int kdst = w * 4096;
  const int vdst = VBASE + w * 4096;

#define ISSUE_K(tt, bufb)                                                      \
  do {                                                                         \
    const char* s_ = KbB + (size_t)(tt) * TILEB;                               \
    _Pragma("unroll")                                                          \
    for (int i_ = 0; i_ < 4; i_++)                                             \
      __builtin_amdgcn_global_load_lds(                                        \
          (const AS1 unsigned int*)(s_ + koff[i_]),                            \
          (AS3 unsigned int*)(smem + (bufb) + kdst + i_ * 1024), 16, 0, 0);    \
  } while (0)

#define ISSUE_V(tt)                                                            \
  do {                                                                         \
    const char* s_ = VtB + (size_t)(tt) * TILEB;                               \
    _Pragma("unroll")                                                          \
    for (int i_ = 0; i_ < 4; i_++)                                             \
      __builtin_amdgcn_global_load_lds(                                        \
          (const AS1 unsigned int*)(s_ + voff[i_]),                            \
          (AS3 unsigned int*)(smem + vdst + i_ * 1024), 16, 0, 0);             \
  } while (0)

  // Q fragments (B-operand): frag kf element jj <-> d = 16*kf + 8*h + jj
  short8 qf[8];
  {
    const float* qsrc = Q + ((size_t)b * S_LEN + qrow) * D_DIM + 8 * h;
#pragma unroll
    for (int kf = 0; kf < 8; kf++) {
      float4 a = *reinterpret_cast<const float4*>(qsrc + 16 * kf);
      float4 d = *reinterpret_cast<const float4*>(qsrc + 16 * kf + 4);
      union { short8 v; unsigned int u[4]; } q8;
      q8.u[0] = cvtpk(a.x * QSC, a.y * QSC);
      q8.u[1] = cvtpk(a.z * QSC, a.w * QSC);
      q8.u[2] = cvtpk(d.x * QSC, d.y * QSC);
      q8.u[3] = cvtpk(d.z * QSC, d.w * QSC);
      qf[kf] = q8.v;
    }
  }

  f32x16 acc[4];
#pragma unroll
  for (int nt = 0; nt < 4; nt++)
#pragma unroll
    for (int rr = 0; rr < 16; rr++) acc[nt][rr] = 0.0f;
  float l_run = 0.0f;

  const int krow = 32 * kq + ln31;
  const int kbase = krow * 256;
  const int ksw = (krow & 15) << 4;

  ISSUE_K(0, 0);
  for (int t = 0; t < T; t++) {
    ISSUE_V(t);
    asm volatile("s_waitcnt vmcnt(4)" ::: "memory");  // own K(t) landed
    __builtin_amdgcn_sched_barrier(0);
    __builtin_amdgcn_s_barrier();                     // all K(t) visible
    __builtin_amdgcn_sched_barrier(0);
    {
      int tn = t + 1;
      if (tn >= T) tn = T - 1;  // uniform count; garbage never read
      ISSUE_K(tn, ((t + 1) & 1) * TILEB);
    }
    const int kbq = 192 * t + 32 * kq;
    const bool act = kbq < kv_end;
    f32x16 sT;
#pragma unroll
    for (int r = 0; r < 16; r++) sT[r] = 0.0f;
    if (act) {
      const char* kb = smem + (t & 1) * TILEB;
      __builtin_amdgcn_s_setprio(1);
#pragma unroll
      for (int kf = 0; kf < 8; kf++) {
        short8 af = *reinterpret_cast<const short8*>(
            kb + kbase + ((32 * kf + 16 * h) ^ ksw));
        sT = __builtin_amdgcn_mfma_f32_32x32x16_bf16(af, qf[kf], sT, 0, 0, 0);
      }
      __builtin_amdgcn_s_setprio(0);
      if (kbq + 31 > q0 + 32 * qs) {
#pragma unroll
        for (int r = 0; r < 16; r++) {
          int kvg = kbq + (r & 3) + 8 * (r >> 2) + 4 * h;
          if (kvg > qrow) sT[r] = 0.0f;  // multiplicative mask; exp gives 2^-8
        }
      }
#pragma unroll
      for (int r = 0; r < 16; r++) sT[r] = EXP2(sT[r] - MFIX);
      float ts[8];
#pragma unroll
      for (int r = 0; r < 8; r++) ts[r] = sT[r] + sT[r + 8];
#pragma unroll
      for (int r = 0; r < 4; r++) ts[r] = ts[r] + ts[r + 4];
      float sum = (ts[0] + ts[1]) + (ts[2] + ts[3]);
      sum = xhalf_sum(sum);
      l_run += sum;
    }
    asm volatile("s_waitcnt vmcnt(4)" ::: "memory");  // own V(t) landed
    __builtin_amdgcn_sched_barrier(0);
    __builtin_amdgcn_s_barrier();                     // all V(t) visible
    __builtin_amdgcn_sched_barrier(0);
    if (act) {
      const char* vb = smem + VBASE;
#pragma unroll
      for (int kl = 0; kl < 2; kl++) {
        const int ra = 8 * kl;
        const int rb = 8 * kl + 4;
        unsigned int a0 = cvtpk(sT[ra + 0], sT[ra + 1]);
        unsigned int a1 = cvtpk(sT[ra + 2], sT[ra + 3]);
        unsigned int b0 = cvtpk(sT[rb + 0], sT[rb + 1]);
        unsigned int b1 = cvtpk(sT[rb + 2], sT[rb + 3]);
        plswap(a0, b0);
        plswap(a1, b1);
        union { short8 v; unsigned int u[4]; } pa;
        pa.u[0] = a0; pa.u[1] = a1; pa.u[2] = b0; pa.u[3] = b1;
        __builtin_amdgcn_s_setprio(1);
#pragma unroll
        for (int nt = 0; nt < 4; nt++) {
          short8 vf = *reinterpret_cast<const short8*>(vb + va[kl * 4 + nt]);
          acc[nt] =
              __builtin_amdgcn_mfma_f32_32x32x16_bf16(pa.v, vf, acc[nt], 0, 0, 0);
        }
        __builtin_amdgcn_s_setprio(0);
      }
    }
    __builtin_amdgcn_sched_barrier(0);
    __builtin_amdgcn_s_barrier();  // WAR: all PV reads of V done before next ISSUE_V
    __builtin_amdgcn_sched_barrier(0);
  }
  __syncthreads();  // drain trailing clamped K loads before overlay

  // ---- 2-round merge (fixed-max => plain sums), then kq==0 stores ----
  float* preg = (float*)smem;            // 6 x 16KB partial slots
  float* lreg = (float*)(smem + LBASE);  // l slots
  // round 1: kq 3,4,5 publish
  if (kq >= 3) {
    float* pr = preg + (qs * 3 + (kq - 3)) * 4096;
#pragma unroll
    for (int nt = 0; nt < 4; nt++)
#pragma unroll
      for (int rr = 0; rr < 16; rr++) {
        int cr = (rr & 3) + 8 * (rr >> 2) + 4 * h;
        pr[cr * 128 + ln31 + 32 * nt] = acc[nt][rr];
      }
    if (h == 0) lreg[(qs * 3 + (kq - 3)) * 32 + ln31] = l_run;
  }
  __syncthreads();
  if (kq < 3) {
    const float* pr = preg + (qs * 3 + kq) * 4096;
#pragma unroll
    for (int nt = 0; nt < 4; nt++)
#pragma unroll
      for (int rr = 0; rr < 16; rr++) {
        int cr = (rr & 3) + 8 * (rr >> 2) + 4 * h;
        acc[nt][rr] += pr[cr * 128 + ln31 + 32 * nt];
      }
    l_run += lreg[(qs * 3 + kq) * 32 + ln31];
  }
  __syncthreads();
  // round 2: kq 1,2 publish
  if (kq == 1 || kq == 2) {
    float* pr = preg + (qs * 2 + (kq - 1)) * 4096;
#pragma unroll
    for (int nt = 0; nt < 4; nt++)
#pragma unroll
      for (int rr = 0; rr < 16; rr++) {
        int cr = (rr & 3) + 8 * (rr >> 2) + 4 * h;
        pr[cr * 128 + ln31 + 32 * nt] = acc[nt][rr];
      }
    if (h == 0) lreg[(qs * 2 + (kq - 1)) * 32 + ln31] = l_run;
  }
  __syncthreads();
  if (kq == 0) {
    const float* p0 = preg + (qs * 2 + 0) * 4096;
    const float* p1 = preg + (qs * 2 + 1) * 4096;
    float l_tot = l_run + lreg[(qs * 2 + 0) * 32 + ln31] +
                  lreg[(qs * 2 + 1) * 32 + ln31] + (float)(S_LEN - kv_end) * E8;
    const float* sv = SufV + ((size_t)b * 33 + (kv_end >> 6)) * 128;
    float* ob = out + ((size_t)b * S_LEN + q0 + 32 * qs) * D_DIM + ln31;
#pragma unroll
    for (int nt = 0; nt < 4; nt++) {
      float svv = sv[ln31 + 32 * nt];
#pragma unroll
      for (int rr = 0; rr < 16; rr++) {
        int cr = (rr & 3) + 8 * (rr >> 2) + 4 * h;
        int cidx = cr * 128 + ln31 + 32 * nt;
        float v = acc[nt][rr] + p0[cidx] + p1[cidx] + E8 * svv;
        float lq = __shfl(l_tot, cr);
        ob[(size_t)cr * D_DIM + 32 * nt] = v / lq;
      }
    }
  }
  __syncthreads();  // protect overlay before next strip's staging
#undef ISSUE_K
#undef ISSUE_V
}

__global__ __launch_bounds__(768, 3) void attn_kernel(
    const float* __restrict__ Q, const unsigned short* __restrict__ Kb,
    const unsigned short* __restrict__ Vt, const float* __restrict__ SufV,
    float* __restrict__ out) {
  __shared__ __align__(16) char smem[SMEM_BYTES];

  const int tid = threadIdx.x;
  const int w = tid >> 6, lane = tid & 63;
  const int ln31 = lane & 31, h = lane >> 5;
  const int qs = (w >= 6) ? 1 : 0;
  const int kq = w - 6 * qs;

  // decode: XCD x owns batches {2x,2x+1}; block = (b, pair p): strips 31-p, p
  const int bid = blockIdx.x;
  const int x = bid & 7, idx = bid >> 3;
  const int b = 2 * x + (idx & 1);
  const int p = idx >> 1;

  // staging source offsets (pre-swizzled involutions; imm=0; dest lane-linear)
  int koff[4], voff[4];
#pragma unroll
  for (int i = 0; i < 4; i++) {
    const int L = w * 4096 + i * 1024 + lane * 16;
    const int rk = L >> 8;  // K: 256B rows, 16-slot swizzle
    koff[i] = rk * 256 + ((L & 255) ^ ((rk & 15) << 4));
    const int rv = L / 384;  // V: 384B rows, 8-slot swizzle
    const int ov = L - rv * 384;
    voff[i] = rv * 384 + (ov ^ ((rv & 7) << 4));
  }
  const char* KbB = (const char*)(Kb + (size_t)b * S_LEN * D_DIM);
  const char* VtB = (const char*)(Vt + (size_t)b * (NT192 * 128 * 192));

  // hoisted V-fragment read offsets
  int va[8];
#pragma unroll
  for (int kl = 0; kl < 2; kl++)
#pragma unroll
    for (int nt = 0; nt < 4; nt++) {
      const int rv = ln31 + 32 * nt;
      va[kl * 4 + nt] = rv * 384 + ((64 * kq + 32 * kl + 16 * h) ^ ((rv & 7) << 4));
    }

  run_strip(31 - p, b, smem, Q, SufV, out, KbB, VtB, koff, voff, va, w, lane,
            ln31, h, qs, kq);
  run_strip(p, b, smem, Q, SufV, out, KbB, VtB, koff, voff, va, w, lane, ln31,
            h, qs, kq);
}

// ---------------- launcher ----------------

extern "C" void kernel_launch(void* const* d_in, const int* in_sizes, int n_in,
                              void* d_out, int out_size, void* d_ws, size_t ws_size,
                              hipStream_t stream) {
  const float* Q = (const float*)d_in[0];
  const float* K = (const float*)d_in[1];
  const float* V = (const float*)d_in[2];
  float* out = (float*)d_out;

  char* ws = (char*)d_ws;
  unsigned short* Kb = (unsigned short*)ws;                    // 8 MiB
  unsigned short* Vt = Kb + 4194304;                           // 8.25 MiB (192-tiles)
  float* Tsum = (float*)(ws + 8388608 + 8650752);              // 256 KiB
  float* SufV = Tsum + 65536;                                  // 264 KiB

  prep<<<3072, 256, 0, stream>>>(K, V, Kb, Vt, Tsum);
  sufB<<<16, 128, 0, stream>>>(Tsum, SufV);
  attn_kernel<<<256, 768, 0, stream>>>(Q, Kb, Vt, SufV, out);
}

// Round 17
// 59.461 us; speedup vs baseline: 1.2264x; 1.2264x over previous
//
#include <hip/hip_runtime.h>
#include <hip/hip_bf16.h>

#define DEVI static __device__ __forceinline__

typedef __attribute__((ext_vector_type(8))) short short8;
typedef __attribute__((ext_vector_type(16))) float f32x16;
typedef __attribute__((ext_vector_type(2))) unsigned int uintx2;

#define S_LEN 2048
#define D_DIM 128
#define NBATCH 16
// (1/sqrt(128)) * log2(e): base-2 softmax, scale folded into Q conversion
#define QSC ((float)(0.08838834764831845 * 1.4426950408889634))
// fixed softmax shift: P = 2^(score - 8); exact by shift-invariance
#define MFIX 8.0f
#define E8 0.00390625f  // 2^-8, weight of a masked (score 0) position

#if __has_builtin(__builtin_amdgcn_exp2f)
#define EXP2(x) __builtin_amdgcn_exp2f(x)
#else
#define EXP2(x) exp2f(x)
#endif

DEVI unsigned short f2bf(float x) {
  union { float f; unsigned int u; } a; a.f = x;
  unsigned int u = a.u;
  unsigned int r = (u + 0x7fffu + ((u >> 16) & 1u)) >> 16;
  return (unsigned short)r;
}

DEVI unsigned int cvtpk(float lo, float hi) {
  unsigned int r;
  asm volatile("v_cvt_pk_bf16_f32 %0, %1, %2" : "=v"(r) : "v"(lo), "v"(hi));
  return r;
}

// v_permlane32_swap_b32: post: a = {a.lo | b.lo}, b = {a.hi | b.hi}  (R4-verified)
DEVI void plswap(unsigned int& a, unsigned int& b) {
  uintx2 r = __builtin_amdgcn_permlane32_swap(a, b, false, false);
  a = r[0];
  b = r[1];
}

DEVI float xhalf_sum(float x) {
  union { float f; unsigned int u; } a, b;
  a.f = x; b.f = x;
  plswap(a.u, b.u);
  return a.f + b.f;
}

// ---------------- prepass ----------------

// blocks [0,1024): V [b][s][d] fp32 -> Vt 128-key-tile-major [b][t:16][d:128][128keys]
//                  bf16 + per-32-row tile sums (32-granular for per-wave tails)
// blocks [1024,3072): K fp32 -> bf16 (row-major unchanged)
__global__ void prep(const float* __restrict__ K, const float* __restrict__ V,
                     unsigned short* __restrict__ Kb, unsigned short* __restrict__ Vt,
                     float* __restrict__ Tsum) {
  __shared__ unsigned short t[64][68];
  const int tt = threadIdx.x;
  if (blockIdx.x >= 1024) {
    const int M4 = (NBATCH * S_LEN * D_DIM) / 4;
    for (int i = (blockIdx.x - 1024) * 256 + tt; i < M4; i += 2048 * 256) {
      const size_t idx = (size_t)i * 4;
      const float4 v = *reinterpret_cast<const float4*>(K + idx);
      ushort4 o;
      o.x = f2bf(v.x); o.y = f2bf(v.y); o.z = f2bf(v.z); o.w = f2bf(v.w);
      *reinterpret_cast<ushort4*>(Kb + idx) = o;
    }
    return;
  }
  const int bid = blockIdx.x;
  const int b = bid >> 6, rem = bid & 63;
  const int st = rem & 31, s0 = st * 64, d0 = (rem >> 5) * 64;
  const int r = tt >> 2, c = (tt & 3) * 16;
  const float* src = V + ((size_t)(b * S_LEN + s0 + r)) * D_DIM + d0 + c;
#pragma unroll
  for (int i = 0; i < 4; i++) {
    float4 v = reinterpret_cast<const float4*>(src)[i];
    t[r][c + 4 * i + 0] = f2bf(v.x);
    t[r][c + 4 * i + 1] = f2bf(v.y);
    t[r][c + 4 * i + 2] = f2bf(v.z);
    t[r][c + 4 * i + 3] = f2bf(v.w);
  }
  __syncthreads();
  // 128-key tile: Vt[((b*16 + (st>>1))*128 + d)*128 + (st&1)*64 + key]
  unsigned short* dst =
      Vt + (((size_t)(b * 16 + (st >> 1))) * 128 + d0 + r) * 128 + (st & 1) * 64 + c;
#pragma unroll
  for (int i = 0; i < 4; i++) {
    ushort4 o;
    o.x = t[c + 4 * i + 0][r];
    o.y = t[c + 4 * i + 1][r];
    o.z = t[c + 4 * i + 2][r];
    o.w = t[c + 4 * i + 3][r];
    reinterpret_cast<ushort4*>(dst)[i] = o;
  }
  // 32-granular column sums: tile32 = st*2 + half (keys 32*tile32..+31)
  if (tt < 128) {
    const int half = tt >> 6, dc = tt & 63;
    float s = 0.0f;
#pragma unroll 8
    for (int rr = 0; rr < 32; rr++) {
      union { float f; unsigned int u; } cv;
      cv.u = ((unsigned int)t[half * 32 + rr][dc]) << 16;
      s += cv.f;
    }
    Tsum[((size_t)(b * 64 + st * 2 + half)) * 128 + d0 + dc] = s;
  }
}

// SufV[b][t][d] = sum_{t' >= t} Tsum[b][t'][d] over 64 32-key tiles; SufV[b][64][d]=0
__global__ void sufB(const float* __restrict__ Tsum, float* __restrict__ SufV) {
  const int b = blockIdx.x;
  const int d = threadIdx.x;
  float v[64];
#pragma unroll
  for (int t = 0; t < 64; t++) v[t] = Tsum[((size_t)b * 64 + t) * 128 + d];
  float run = 0.0f;
  SufV[((size_t)b * 65 + 64) * 128 + d] = 0.0f;
#pragma unroll
  for (int t = 63; t >= 0; t--) {
    run += v[t];
    SufV[((size_t)b * 65 + t) * 128 + d] = run;
  }
}

// ---------------- attention kernel ----------------

#define AS1 __attribute__((address_space(1)))
#define AS3 __attribute__((address_space(3)))

// fixed-max 32-key chunk: P = 2^(s-8); R15-verified fragment/swizzle formulas
template <bool MASK>
DEVI void chunk_body(const char* kb, const char* vb, const int kq,
                     const short8* qf, f32x16 (&acc)[4], float& l_run,
                     const int ln31, const int h, const int qrow, const int kbq) {
  const int krow = 32 * kq + ln31;
  const int ksw = (krow & 15) << 4;
  const char* kbase = kb + krow * 256;
  f32x16 sT;
#pragma unroll
  for (int r = 0; r < 16; r++) sT[r] = 0.0f;
  __builtin_amdgcn_s_setprio(1);
#pragma unroll
  for (int kf = 0; kf < 8; kf++) {
    short8 af = *reinterpret_cast<const short8*>(kbase + ((32 * kf + 16 * h) ^ ksw));
    sT = __builtin_amdgcn_mfma_f32_32x32x16_bf16(af, qf[kf], sT, 0, 0, 0);
  }
  __builtin_amdgcn_s_setprio(0);
  if (MASK) {
#pragma unroll
    for (int r = 0; r < 16; r++) {
      int kvg = kbq + (r & 3) + 8 * (r >> 2) + 4 * h;
      if (kvg > qrow) sT[r] = 0.0f;  // multiplicative mask; exp gives 2^-8
    }
  }
#pragma unroll
  for (int r = 0; r < 16; r++) sT[r] = EXP2(sT[r] - MFIX);
  float ts[8];
#pragma unroll
  for (int r = 0; r < 8; r++) ts[r] = sT[r] + sT[r + 8];
#pragma unroll
  for (int r = 0; r < 4; r++) ts[r] = ts[r] + ts[r + 4];
  float sum = (ts[0] + ts[1]) + (ts[2] + ts[3]);
  sum = xhalf_sum(sum);
  l_run += sum;
  // pack P -> bf16 A-fragments: u[0]={a.lo|b.lo}, u[2]={a.hi|b.hi} (R4-verified)
  const int vsw = (ln31 & 15) << 4;  // (ln31+32nt)&15 == ln31&15
#pragma unroll
  for (int kl = 0; kl < 2; kl++) {
    const int ra = 8 * kl;
    const int rb = 8 * kl + 4;
    unsigned int a0 = cvtpk(sT[ra + 0], sT[ra + 1]);
    unsigned int a1 = cvtpk(sT[ra + 2], sT[ra + 3]);
    unsigned int b0 = cvtpk(sT[rb + 0], sT[rb + 1]);
    unsigned int b1 = cvtpk(sT[rb + 2], sT[rb + 3]);
    plswap(a0, b0);
    plswap(a1, b1);
    union { short8 v; unsigned int u[4]; } pa;
    pa.u[0] = a0; pa.u[1] = a1; pa.u[2] = b0; pa.u[3] = b1;
    const int vo = (64 * kq + 32 * kl + 16 * h) ^ vsw;
    __builtin_amdgcn_s_setprio(1);
#pragma unroll
    for (int nt = 0; nt < 4; nt++) {
      short8 vf = *reinterpret_cast<const short8*>(vb + (ln31 + 32 * nt) * 256 + vo);
      acc[nt] = __builtin_amdgcn_mfma_f32_32x32x16_bf16(pa.v, vf, acc[nt], 0, 0, 0);
    }
    __builtin_amdgcn_s_setprio(0);
  }
}

// LDS: 2 buffers x (K 32KB + V 32KB) = 128KB; epilogue overlays 4x16KB partials
// at [0,64K) + l rows at 128K (512B).
#define SMEM_BYTES 132096

__global__ __launch_bounds__(512, 2) void attn_kernel(
    const float* __restrict__ Q, const unsigned short* __restrict__ Kb,
    const unsigned short* __restrict__ Vt, const float* __restrict__ SufV,
    float* __restrict__ out) {
  __shared__ __align__(16) char smem[SMEM_BYTES];

  const int tid = threadIdx.x;
  const int w = tid >> 6, lane = tid & 63;
  const int ln31 = lane & 31, h = lane >> 5;
  const int qq = w >> 1;  // q quarter: rows [q0+32*qq, +32)
  const int kh = w & 1;   // key half of each 128-key tile (2 chunks each)

  // decode: XCD x owns batches {2x,2x+1}; 128-row group g, LPT (g=15 first)
  const int bid = blockIdx.x;
  const int x = bid & 7, r = bid >> 3;  // r 0..31
  const int b = 2 * x + (r & 1);
  const int g = 15 - (r >> 1);
  const int q0 = g * 128;
  const int T = g + 1;  // 128-key tiles
  const int qrow = q0 + 32 * qq + ln31;

  // staging: waves 0-3 stage K 32KB (part w), waves 4-7 stage V^T 32KB.
  // 256B rows, 16-slot XOR swizzle pre-applied on the source (involution).
  const int part = w & 3;
  int off[8];
#pragma unroll
  for (int i = 0; i < 8; i++) {
    int L = (part * 8 + i) * 1024 + lane * 16;
    int row = L >> 8;
    off[i] = row * 256 + ((L & 255) ^ ((row & 15) << 4));
  }
  const char* tbase;
  int dstpart;
  if (w < 4) {
    tbase = (const char*)(Kb + (size_t)b * S_LEN * D_DIM);
    dstpart = part * 8192;
  } else {
    tbase = (const char*)(Vt + (size_t)b * S_LEN * D_DIM);
    dstpart = 32768 + part * 8192;
  }

#define STAGE(t, bufb)                                                         \
  do {                                                                         \
    const char* src_ = tbase + (size_t)(t) * 32768;                            \
    _Pragma("unroll")                                                          \
    for (int i_ = 0; i_ < 8; i_++) {                                           \
      __builtin_amdgcn_global_load_lds(                                        \
          (const AS1 unsigned int*)(src_ + off[i_]),                           \
          (AS3 unsigned int*)(smem + (bufb) + dstpart + i_ * 1024), 16, 0, 0); \
    }                                                                          \
  } while (0)

  // Q fragments (B-operand): frag kf element jj <-> d = 16*kf + 8*h + jj
  short8 qf[8];
  {
    const float* qsrc = Q + ((size_t)b * S_LEN + qrow) * D_DIM + 8 * h;
#pragma unroll
    for (int kf = 0; kf < 8; kf++) {
      float4 a = *reinterpret_cast<const float4*>(qsrc + 16 * kf);
      float4 d = *reinterpret_cast<const float4*>(qsrc + 16 * kf + 4);
      union { short8 v; unsigned int u[4]; } q8;
      q8.u[0] = cvtpk(a.x * QSC, a.y * QSC);
      q8.u[1] = cvtpk(a.z * QSC, a.w * QSC);
      q8.u[2] = cvtpk(d.x * QSC, d.y * QSC);
      q8.u[3] = cvtpk(d.z * QSC, d.w * QSC);
      qf[kf] = q8.v;
    }
  }

  f32x16 acc[4];
#pragma unroll
  for (int nt = 0; nt < 4; nt++)
#pragma unroll
    for (int rr = 0; rr < 16; rr++) acc[nt][rr] = 0.0f;
  float l_run = 0.0f;

  // main loop: stage(t+1) || compute(t); one barrier pair per phase (R9/R15)
  STAGE(0, 0);
  __syncthreads();
  for (int t = 0; t < T; t++) {
    const int bb = (t & 1) << 16;
    if (t + 1 < T) STAGE(t + 1, bb ^ 65536);
    const char* kb = smem + bb;
    const char* vb = smem + bb + 32768;
#pragma unroll
    for (int c = 0; c < 2; c++) {
      const int kq = 2 * kh + c;
      const int kbq = 128 * t + 32 * kq;
      if (kbq <= q0 + 32 * qq) {
        if (kbq == q0 + 32 * qq)  // exact diagonal 32x32 chunk
          chunk_body<true>(kb, vb, kq, qf, acc, l_run, ln31, h, qrow, kbq);
        else
          chunk_body<false>(kb, vb, kq, qf, acc, l_run, ln31, h, qrow, kbq);
      }
    }
    __syncthreads();
  }

  // epilogue: kh=1 publishes acc+l per qq slot; kh=0 merges + tail + store.
  // Per-wave key coverage ends at end_w = q0+32*qq+32 (32-aligned).
  float* pbase = (float*)smem + qq * 4096;  // 4 slots x 16KB
  float* lsh = (float*)(smem + 131072);
  if (kh == 1) {
#pragma unroll
    for (int nt = 0; nt < 4; nt++)
#pragma unroll
      for (int rr = 0; rr < 16; rr++) {
        int cr = (rr & 3) + 8 * (rr >> 2) + 4 * h;
        pbase[cr * 128 + ln31 + 32 * nt] = acc[nt][rr];
      }
    if (h == 0) lsh[qq * 32 + ln31] = l_run;
  }
  __syncthreads();
  if (kh == 0) {
    const int end_w = q0 + 32 * qq + 32;
    float l_tot = l_run + lsh[qq * 32 + ln31] + (float)(S_LEN - end_w) * E8;
    const float* sv = SufV + ((size_t)b * 65 + (end_w >> 5)) * 128;
    float* ob = out + ((size_t)b * S_LEN + q0 + 32 * qq) * D_DIM + ln31;
#pragma unroll
    for (int nt = 0; nt < 4; nt++) {
      float svv = sv[ln31 + 32 * nt];
#pragma unroll
      for (int rr = 0; rr < 16; rr++) {
        int cr = (rr & 3) + 8 * (rr >> 2) + 4 * h;
        float v = acc[nt][rr] + pbase[cr * 128 + ln31 + 32 * nt] + E8 * svv;
        float lq = __shfl(l_tot, cr);
        ob[(size_t)cr * D_DIM + 32 * nt] = v / lq;
      }
    }
  }
}

// ---------------- launcher ----------------

extern "C" void kernel_launch(void* const* d_in, const int* in_sizes, int n_in,
                              void* d_out, int out_size, void* d_ws, size_t ws_size,
                              hipStream_t stream) {
  const float* Q = (const float*)d_in[0];
  const float* K = (const float*)d_in[1];
  const float* V = (const float*)d_in[2];
  float* out = (float*)d_out;

  char* ws = (char*)d_ws;
  unsigned short* Kb = (unsigned short*)ws;                 // 8 MiB
  unsigned short* Vt = Kb + 4194304;                        // 8 MiB (128-key tiles)
  float* Tsum = (float*)(ws + 16777216);                    // 512 KiB (32-granular)
  float* SufV = Tsum + 131072;                              // 532 KiB

  prep<<<3072, 256, 0, stream>>>(K, V, Kb, Vt, Tsum);
  sufB<<<16, 128, 0, stream>>>(Tsum, SufV);
  attn_kernel<<<256, 512, 0, stream>>>(Q, Kb, Vt, SufV, out);
}